// Round 16
// baseline (704.025 us; speedup 1.0000x reference)
//
#include <hip/hip_runtime.h>
#include <math.h>
#include <stdint.h>

#define BB    4
#define QQ    200
#define NGT   32
#define DD    65536   // 256*256
#define TOPK  4
#define EPSF  1e-6f
#define QP    208     // padded Q stride

#define QT16  13      // ceil(200/16) q-tiles of 16
#define KG    32      // K-split: wg covers DD/KG = 2048 k
#define KSPAN (DD / KG)       // 2048
#define BK    256             // k per staged chunk (16 rows x 1 KB)
#define NCH   (KSPAN / BK)    // 8 chunks
#define NWG2  (BB * QT16 * KG)             // 1664 wgs in L2
#define ZCNT  (BB*NGT + BB*NGT*QP + BB*QP + 1)   // tsum+inter+psum+done

typedef float  f32x4  __attribute__((ext_vector_type(4)));
typedef __bf16 bf16x8 __attribute__((ext_vector_type(8)));

#define PERM_HI16 0x07060302u   // [a.hi16 : b.hi16]
#define PERM_LO16 0x05040100u   // [a.lo16 : b.lo16]

#define RAW_BARRIER() asm volatile("s_barrier" ::: "memory")
#define VM_DRAIN()    asm volatile("s_waitcnt vmcnt(0)" ::: "memory")

// async global->LDS DMA, 16 B per lane; LDS dest = uniform base + lane*16.
#define GLOAD_LDS16(gptr, lptr)                                                  \
    __builtin_amdgcn_global_load_lds(                                            \
        (const __attribute__((address_space(1))) uint32_t*)(gptr),               \
        (__attribute__((address_space(3))) uint32_t*)(lptr), 16, 0, 0)

// ---------------------------------------------------------------------------
// L1: bit-pack gt_masks -> packed[b][d] (bit n = gt[b,n,d]); fused zero-init
// of tsum+inter+psum+done (ws is poisoned before every timed call).
__global__ __launch_bounds__(256) void k_pack(const float* __restrict__ gt,
                                              uint32_t* __restrict__ packed,
                                              float* __restrict__ zero_base) {
    int zidx = blockIdx.x * 256 + threadIdx.x;
    if (zidx < ZCNT) zero_base[zidx] = 0.0f;

    int blk = blockIdx.x;
    int b = blk >> 6;
    int d0 = ((blk & 63) * 256 + threadIdx.x) * 4;
    uint32_t px = 0, py = 0, pz = 0, pw = 0;
    const float* gb = gt + (size_t)b * NGT * DD + d0;
#pragma unroll
    for (int n = 0; n < NGT; ++n) {
        float4 g = *(const float4*)(gb + (size_t)n * DD);
        px |= (g.x > 0.5f ? 1u : 0u) << n;
        py |= (g.y > 0.5f ? 1u : 0u) << n;
        pz |= (g.z > 0.5f ? 1u : 0u) << n;
        pw |= (g.w > 0.5f ? 1u : 0u) << n;
    }
    *(uint4*)(packed + (size_t)b * DD + d0) = make_uint4(px, py, pz, pw);
}

// ---------------------------------------------------------------------------
// L2: MFMA main (r15 DMA structure, unchanged) + fused tsum (qt==0 wgs,
// ballot-popcount of this kg's 2048 packed words) + fused top4/dedup match
// run by the LAST wg (done-ticket pattern; deadlock-free — no spin).
// Cross-wg visibility without kernel boundaries: inter/psum/tsum written via
// device-scope atomics; the match phase READS them via atomicAdd(p, 0.0f)
// atomic-loads (plain loads could hit stale per-XCD L2 lines cached by the
// zero-init/poison, since device-scope atomics bypass L2).
__global__ __launch_bounds__(256) void k_mfma(const float* __restrict__ pm,
                                              const uint32_t* __restrict__ packed,
                                              float* __restrict__ inter,   // [B][32][QP]
                                              float* __restrict__ psum,    // [B][QP]
                                              float* __restrict__ tsum,    // [B][32]
                                              const float* __restrict__ logits,
                                              int* __restrict__ done,
                                              int* __restrict__ out) {
    int blk = blockIdx.x;
    int b   = blk / (QT16 * KG);
    int rem = blk % (QT16 * KG);
    int qt  = rem / KG;
    int kg  = rem % KG;
    int tid = threadIdx.x, lane = tid & 63, wave = tid >> 6;
    int m = lane & 15, quad = lane >> 4;   // m: A-row / C-col(n) / B-bit

    __shared__ float sA[2][16][BK];        // 32 KB, linear (DMA dest)

    const float*    pmb = pm + (size_t)b * QQ * DD + (size_t)kg * KSPAN;
    const uint32_t* pkb = packed + (size_t)b * DD + (size_t)kg * KSPAN;

    // fused tsum partials: qt==0 wgs only (~600 cy; 32 atomics/wave)
    if (qt == 0) {
        uint32_t w8[8];
#pragma unroll
        for (int j = 0; j < 8; ++j) w8[j] = pkb[tid + 256 * j];
#pragma unroll
        for (int n = 0; n < NGT; ++n) {
            int c = 0;
#pragma unroll
            for (int j = 0; j < 8; ++j)
                c += __popcll(__ballot((w8[j] >> n) & 1u));
            if (lane == 0) atomicAdd(&tsum[b * NGT + n], (float)c);
        }
    }

    int row0 = wave * 4;                   // this wave stages rows row0..row0+3
    int qrow[4];
#pragma unroll
    for (int i = 0; i < 4; ++i) {
        int qg = qt * 16 + row0 + i;
        qrow[i] = qg < QQ ? qg : QQ - 1;   // clamped rows masked at output
    }

    f32x4 cH0 = {0.f,0.f,0.f,0.f}, cL0 = {0.f,0.f,0.f,0.f};
    f32x4 cH1 = {0.f,0.f,0.f,0.f}, cL1 = {0.f,0.f,0.f,0.f};
    float ps = 0.f;

    // ---- prologue: DMA chunk 0 into buf 0
#pragma unroll
    for (int i = 0; i < 4; ++i) {
        int r = row0 + i;
        const float* gsrc = pmb + (size_t)qrow[i] * DD + ((lane ^ (r & 7)) << 2);
        GLOAD_LDS16(gsrc, &sA[0][r][0]);
    }
    VM_DRAIN();
    RAW_BARRIER();

    for (int c = 0; c < NCH; ++c) {
        int buf = c & 1;
        if (c + 1 < NCH) {
#pragma unroll
            for (int i = 0; i < 4; ++i) {
                int r = row0 + i;
                const float* gsrc = pmb + (size_t)qrow[i] * DD
                                        + (size_t)(c + 1) * BK + ((lane ^ (r & 7)) << 2);
                GLOAD_LDS16(gsrc, &sA[buf ^ 1][r][0]);
            }
        }

#pragma unroll
        for (int st = 0; st < 2; ++st) {
            int k0 = wave * 64 + st * 32 + quad * 8;
            int c0 = k0 >> 2;
            float4 a0 = *(const float4*)&sA[buf][m][(c0 ^ (m & 7)) << 2];
            float4 a1 = *(const float4*)&sA[buf][m][((c0 + 1) ^ (m & 7)) << 2];
            const uint32_t* bpc = pkb + (size_t)c * BK + k0;
            uint4 w0 = *(const uint4*)(bpc);
            uint4 w1 = *(const uint4*)(bpc + 4);

            float xs[8] = {a0.x, a0.y, a0.z, a0.w, a1.x, a1.y, a1.z, a1.w};
            uint32_t hu[8], mu[8], lu[8];
#pragma unroll
            for (int i = 0; i < 8; ++i) {
                float x  = xs[i];
                float sg = __builtin_amdgcn_rcpf(1.0f + __expf(-x));
                ps += sg;
                uint32_t u0 = __float_as_uint(sg);
                float hi = __uint_as_float(u0 & 0xFFFF0000u);
                float r1 = sg - hi;
                uint32_t u1 = __float_as_uint(r1);
                float mi = __uint_as_float(u1 & 0xFFFF0000u);
                float r2 = r1 - mi;
                hu[i] = u0; mu[i] = u1; lu[i] = __float_as_uint(r2);
            }
            union { uint4 u; bf16x8 v; } ah, am, al;
            ah.u = make_uint4(__builtin_amdgcn_perm(hu[1], hu[0], PERM_HI16),
                              __builtin_amdgcn_perm(hu[3], hu[2], PERM_HI16),
                              __builtin_amdgcn_perm(hu[5], hu[4], PERM_HI16),
                              __builtin_amdgcn_perm(hu[7], hu[6], PERM_HI16));
            am.u = make_uint4(__builtin_amdgcn_perm(mu[1], mu[0], PERM_HI16),
                              __builtin_amdgcn_perm(mu[3], mu[2], PERM_HI16),
                              __builtin_amdgcn_perm(mu[5], mu[4], PERM_HI16),
                              __builtin_amdgcn_perm(mu[7], mu[6], PERM_HI16));
            al.u = make_uint4(__builtin_amdgcn_perm(lu[1], lu[0], PERM_HI16),
                              __builtin_amdgcn_perm(lu[3], lu[2], PERM_HI16),
                              __builtin_amdgcn_perm(lu[5], lu[4], PERM_HI16),
                              __builtin_amdgcn_perm(lu[7], lu[6], PERM_HI16));

            uint32_t wj[8] = {w0.x, w0.y, w0.z, w0.w, w1.x, w1.y, w1.z, w1.w};
            uint32_t ob[8];
#pragma unroll
            for (int j = 0; j < 8; ++j) {
                uint32_t t = wj[j] >> m;
                ob[j] = (t & 0x10001u) * 0x3F80u;
            }
            union { uint4 u; bf16x8 v; } b0, b1;
            b0.u = make_uint4(__builtin_amdgcn_perm(ob[1], ob[0], PERM_LO16),
                              __builtin_amdgcn_perm(ob[3], ob[2], PERM_LO16),
                              __builtin_amdgcn_perm(ob[5], ob[4], PERM_LO16),
                              __builtin_amdgcn_perm(ob[7], ob[6], PERM_LO16));
            b1.u = make_uint4(__builtin_amdgcn_perm(ob[1], ob[0], PERM_HI16),
                              __builtin_amdgcn_perm(ob[3], ob[2], PERM_HI16),
                              __builtin_amdgcn_perm(ob[5], ob[4], PERM_HI16),
                              __builtin_amdgcn_perm(ob[7], ob[6], PERM_HI16));

            cH0 = __builtin_amdgcn_mfma_f32_16x16x32_bf16(ah.v, b0.v, cH0, 0, 0, 0);
            cL0 = __builtin_amdgcn_mfma_f32_16x16x32_bf16(am.v, b0.v, cL0, 0, 0, 0);
            cL0 = __builtin_amdgcn_mfma_f32_16x16x32_bf16(al.v, b0.v, cL0, 0, 0, 0);
            cH1 = __builtin_amdgcn_mfma_f32_16x16x32_bf16(ah.v, b1.v, cH1, 0, 0, 0);
            cL1 = __builtin_amdgcn_mfma_f32_16x16x32_bf16(am.v, b1.v, cL1, 0, 0, 0);
            cL1 = __builtin_amdgcn_mfma_f32_16x16x32_bf16(al.v, b1.v, cL1, 0, 0, 0);
        }

        if (c + 1 < NCH) VM_DRAIN();
        RAW_BARRIER();
    }

    // psum: lanes m, m+16, m+32, m+48 share q-row m (disjoint k)
    ps += __shfl_xor(ps, 16);
    ps += __shfl_xor(ps, 32);
    if (lane < 16) {
        int qg = qt * 16 + m;
        if (qg < QQ) atomicAdd(&psum[b * QP + qg], ps);
    }

    // cross-wave C reduce in LDS (stride 9: gcd(9,32)=1), one atomic set/wg.
    float c8[8];
#pragma unroll
    for (int r = 0; r < 4; ++r) {
        c8[r]     = cH0[r] + cL0[r];
        c8[4 + r] = cH1[r] + cL1[r];
    }
    __syncthreads();
    float* cred = (float*)sA;
    if (wave > 0) {
        float* dst = cred + ((wave - 1) * 64 + lane) * 9;
#pragma unroll
        for (int r = 0; r < 8; ++r) dst[r] = c8[r];
    }
    __syncthreads();
    if (wave == 0) {
#pragma unroll
        for (int wv = 0; wv < 3; ++wv) {
            const float* sp = cred + (wv * 64 + lane) * 9;
#pragma unroll
            for (int r = 0; r < 8; ++r) c8[r] += sp[r];
        }
        // C layout (16x16, m89): col(n) = lane&15, row(q) = quad*4 + r
#pragma unroll
        for (int r = 0; r < 4; ++r) {
            int qg = qt * 16 + quad * 4 + r;
            if (qg < QQ) {
                atomicAdd(&inter[(b * NGT + m) * QP + qg],      c8[r]);
                atomicAdd(&inter[(b * NGT + 16 + m) * QP + qg], c8[4 + r]);
            }
        }
    }

    // ---- done-ticket: last wg runs the match (no spin; deadlock-free)
    int* lflag = (int*)sA + 4096;          // byte 16384, past cred & sidx
    int* sidxb = (int*)sA + 2048;          // byte 8192: [4][32][4] ints
    __syncthreads();
    __threadfence();
    if (tid == 0) {
        int t = atomicAdd(done, 1);
        *lflag = (t == NWG2 - 1) ? 1 : 0;
    }
    __syncthreads();
    if (*lflag) {
        __threadfence();
        int mb = wave;                     // 4 waves = 4 batches
        float tsn_l = (lane < NGT) ? atomicAdd(&tsum[mb * NGT + lane], 0.0f) : 0.f;
        float psq[4], cls[4];
#pragma unroll
        for (int s = 0; s < 4; ++s) {
            int q = lane + 64 * s;
            if (q < QQ) {
                psq[s] = atomicAdd(&psum[mb * QP + q], 0.0f);
                float l0 = logits[(mb * QQ + q) * 2];
                float l1 = logits[(mb * QQ + q) * 2 + 1];
                cls[s] = 1.0f / (1.0f + expf(l0 - l1));
            } else { psq[s] = 0.f; cls[s] = 0.f; }
        }
        int* sidxw = sidxb + mb * NGT * TOPK;
        for (int n = 0; n < NGT; ++n) {
            float tsn = __shfl(tsn_l, n);
            float v[4];
#pragma unroll
            for (int s = 0; s < 4; ++s) {
                int q = lane + 64 * s;
                if (q < QQ) {
                    float iv = atomicAdd(&inter[((size_t)mb * NGT + n) * QP + q], 0.0f);
                    float un = psq[s] + tsn - iv;
                    v[s] = iv / (un + EPSF) * cls[s];
                } else v[s] = -INFINITY;
            }
            for (int k = 0; k < TOPK; ++k) {
                float bv = -INFINITY;
                int   bi = 0x7fffffff;
#pragma unroll
                for (int s = 0; s < 4; ++s)
                    if (v[s] > bv) { bv = v[s]; bi = lane + 64 * s; }
#pragma unroll
                for (int off = 32; off; off >>= 1) {
                    float ov = __shfl_xor(bv, off);
                    int   oi = __shfl_xor(bi, off);
                    if (ov > bv || (ov == bv && oi < bi)) { bv = ov; bi = oi; }
                }
                if (lane == (bi & 63)) v[bi >> 6] = -INFINITY;
                if (lane == 0) sidxw[n * TOPK + k] = bi;
            }
        }
        __syncthreads();                   // uniform: lflag is block-uniform
        // greedy dedup, wave-local (b = mb), old K5 logic
        int* src = out;
        int* tgt = out + BB * NGT * TOPK;
        int* val = out + 2 * BB * NGT * TOPK;
        int asg = 0;
        for (int n = 0; n < NGT; ++n) {
            int ids[4] = {sidxw[n * 4], sidxw[n * 4 + 1], sidxw[n * 4 + 2], sidxw[n * 4 + 3]};
            int newasg = asg;
#pragma unroll
            for (int k = 0; k < TOPK; ++k) {
                int idx = ids[k];                      // uniform across lanes
                int owner = idx & 63, slot = idx >> 6;
                int oasg = __shfl(asg, owner);         // pre-n state
                int taken = (oasg >> slot) & 1;
                if (lane == owner) newasg |= (1 << slot);
                if (lane == 0) {
                    int o = (mb * NGT + n) * TOPK + k;
                    src[o] = taken ? -1 : idx;
                    tgt[o] = taken ? -1 : n;
                    val[o] = taken ? 0 : 1;
                }
            }
            asg = newasg;
        }
    }
}

// ---------------------------------------------------------------------------
extern "C" void kernel_launch(void* const* d_in, const int* in_sizes, int n_in,
                              void* d_out, int out_size, void* d_ws, size_t ws_size,
                              hipStream_t stream) {
    const float* pred_masks  = (const float*)d_in[0];  // [4,200,256,256]
    const float* pred_logits = (const float*)d_in[1];  // [4,200,2]
    const float* gt_masks    = (const float*)d_in[2];  // [4,32,256,256]

    uint8_t* ws = (uint8_t*)d_ws;
    uint32_t* packed = (uint32_t*)ws;                   // 1 MB
    float* tsum  = (float*)(ws + (size_t)BB * DD * 4);  // 128 f (zeroed by k_pack)
    float* inter = tsum + BB * NGT;                     // 26624 f (zeroed)
    float* psum  = inter + BB * NGT * QP;               // 832 f  (zeroed)
    int*   done  = (int*)(psum + BB * QP);              // 1 int  (zeroed)

    k_pack<<<BB * (DD / 1024), 256, 0, stream>>>(gt_masks, packed, tsum);
    k_mfma<<<NWG2, 256, 0, stream>>>(pred_masks, packed, inter, psum, tsum,
                                     pred_logits, done, (int*)d_out);
}

// Round 17
// 360.115 us; speedup vs baseline: 1.9550x; 1.9550x over previous
//
#include <hip/hip_runtime.h>
#include <math.h>
#include <stdint.h>

#define BB    4
#define QQ    200
#define NGT   32
#define DD    65536   // 256*256
#define TOPK  4
#define EPSF  1e-6f
#define QP    208     // padded Q stride

#define QT16  13      // ceil(200/16) q-tiles of 16
#define KG    32      // K-split: wg covers DD/KG = 2048 k
#define KSPAN (DD / KG)       // 2048
#define BK    256             // k per staged chunk (16 rows x 1 KB)
#define NCH   (KSPAN / BK)    // 8 chunks
#define NWG   (BB * QT16 * KG)   // 1664 = 8 * 208

typedef float  f32x4  __attribute__((ext_vector_type(4)));
typedef __bf16 bf16x8 __attribute__((ext_vector_type(8)));

#define PERM_HI16 0x07060302u   // [a.hi16 : b.hi16]
#define PERM_LO16 0x05040100u   // [a.lo16 : b.lo16]

#define RAW_BARRIER() asm volatile("s_barrier" ::: "memory")
#define VM_DRAIN()    asm volatile("s_waitcnt vmcnt(0)" ::: "memory")

// async global->LDS DMA, 16 B per lane; LDS dest = uniform base + lane*16.
#define GLOAD_LDS16(gptr, lptr)                                                  \
    __builtin_amdgcn_global_load_lds(                                            \
        (const __attribute__((address_space(1))) uint32_t*)(gptr),               \
        (__attribute__((address_space(3))) uint32_t*)(lptr), 16, 0, 0)

// ---------------------------------------------------------------------------
// K1: bit-pack gt_masks -> packed[b][d] (bit n = gt[b,n,d]); fused zero-init
// of inter+psum (ws is poisoned before every timed call).
__global__ __launch_bounds__(256) void k_pack(const float* __restrict__ gt,
                                              uint32_t* __restrict__ packed,
                                              float* __restrict__ zero_base) {
    int zidx = blockIdx.x * 256 + threadIdx.x;
    if (zidx < BB * NGT * QP + BB * QP) zero_base[zidx] = 0.0f;

    int blk = blockIdx.x;
    int b = blk >> 6;
    int d0 = ((blk & 63) * 256 + threadIdx.x) * 4;
    uint32_t px = 0, py = 0, pz = 0, pw = 0;
    const float* gb = gt + (size_t)b * NGT * DD + d0;
#pragma unroll
    for (int n = 0; n < NGT; ++n) {
        float4 g = *(const float4*)(gb + (size_t)n * DD);
        px |= (g.x > 0.5f ? 1u : 0u) << n;
        py |= (g.y > 0.5f ? 1u : 0u) << n;
        pz |= (g.z > 0.5f ? 1u : 0u) << n;
        pw |= (g.w > 0.5f ? 1u : 0u) << n;
    }
    *(uint4*)(packed + (size_t)b * DD + d0) = make_uint4(px, py, pz, pw);
}

// ---------------------------------------------------------------------------
// K2: tsum[b][n] via popcount-style reduction of packed bits (L2-resident).
__global__ __launch_bounds__(256) void k_tsum(const uint32_t* __restrict__ packed,
                                              float* __restrict__ tsum) {
    int b = blockIdx.x >> 5;
    int n = blockIdx.x & 31;
    const uint4* pp = (const uint4*)(packed + (size_t)b * DD);
    int cnt = 0;
    for (int i = threadIdx.x; i < DD / 4; i += 256) {
        uint4 w = pp[i];
        cnt += (int)((w.x >> n) & 1u) + (int)((w.y >> n) & 1u) +
               (int)((w.z >> n) & 1u) + (int)((w.w >> n) & 1u);
    }
#pragma unroll
    for (int off = 32; off; off >>= 1) cnt += __shfl_xor(cnt, off);
    __shared__ int red[4];
    if ((threadIdx.x & 63) == 0) red[threadIdx.x >> 6] = cnt;
    __syncthreads();
    if (threadIdx.x == 0)
        tsum[blockIdx.x] = (float)(red[0] + red[1] + red[2] + red[3]);
}

// ---------------------------------------------------------------------------
// K3: MFMA main (r15 DMA structure, byte-identical main loop). Round-17
// delta: XCD-contiguity block remap. r16's profile solved the accounting:
// k_mfma ~115 us at 1.8 TB/s effective, invariant across 3 load-path
// structures. Theory: ~590 resident wgs x 16 rows = ~9400 concurrent 1-2KB
// HBM row-streams (rows 256KB apart, each row's 8KB attacked at 32
// kg-offsets) -> page thrash. Fix: blk = (d>>3) + 208*(d&7) (bijective,
// 1664=8*208). With round-robin wg->XCD dispatch, all 32 kg-splits of one
// (b,qt) row-set land on ONE XCD -> each XCD streams whole 8KB rows
// page-coherently through its own L2; distinct concurrent rows ~9400 -> ~256.
__global__ __launch_bounds__(256) void k_mfma(const float* __restrict__ pm,
                                              const uint32_t* __restrict__ packed,
                                              float* __restrict__ inter,   // [B][32][QP]
                                              float* __restrict__ psum) {  // [B][QP]
    int d    = blockIdx.x;
    int blk  = (d >> 3) + 208 * (d & 7);   // XCD-contiguous logical id
    int b   = blk / (QT16 * KG);
    int rem = blk % (QT16 * KG);
    int qt  = rem / KG;
    int kg  = rem % KG;
    int tid = threadIdx.x, lane = tid & 63, wave = tid >> 6;
    int m = lane & 15, quad = lane >> 4;   // m: A-row / C-col(n) / B-bit

    __shared__ float sA[2][16][BK];        // 32 KB, linear (DMA dest)

    const float*    pmb = pm + (size_t)b * QQ * DD + (size_t)kg * KSPAN;
    const uint32_t* pkb = packed + (size_t)b * DD + (size_t)kg * KSPAN;

    int row0 = wave * 4;                   // this wave stages rows row0..row0+3
    int qrow[4];
#pragma unroll
    for (int i = 0; i < 4; ++i) {
        int qg = qt * 16 + row0 + i;
        qrow[i] = qg < QQ ? qg : QQ - 1;   // clamped rows masked at output
    }

    f32x4 cH0 = {0.f,0.f,0.f,0.f}, cL0 = {0.f,0.f,0.f,0.f};
    f32x4 cH1 = {0.f,0.f,0.f,0.f}, cL1 = {0.f,0.f,0.f,0.f};
    float ps = 0.f;

    // ---- prologue: DMA chunk 0 into buf 0
#pragma unroll
    for (int i = 0; i < 4; ++i) {
        int r = row0 + i;
        const float* gsrc = pmb + (size_t)qrow[i] * DD + ((lane ^ (r & 7)) << 2);
        GLOAD_LDS16(gsrc, &sA[0][r][0]);
    }
    VM_DRAIN();
    RAW_BARRIER();

    for (int c = 0; c < NCH; ++c) {
        int buf = c & 1;
        // issue DMA for chunk c+1 into the other buffer (overlaps compute)
        if (c + 1 < NCH) {
#pragma unroll
            for (int i = 0; i < 4; ++i) {
                int r = row0 + i;
                const float* gsrc = pmb + (size_t)qrow[i] * DD
                                        + (size_t)(c + 1) * BK + ((lane ^ (r & 7)) << 2);
                GLOAD_LDS16(gsrc, &sA[buf ^ 1][r][0]);
            }
        }

        // compute chunk c: wave covers k in [wave*64, wave*64+64)
#pragma unroll
        for (int st = 0; st < 2; ++st) {
            int k0 = wave * 64 + st * 32 + quad * 8;       // within chunk
            int c0 = k0 >> 2;                              // 16-B chunk index
            float4 a0 = *(const float4*)&sA[buf][m][(c0 ^ (m & 7)) << 2];
            float4 a1 = *(const float4*)&sA[buf][m][((c0 + 1) ^ (m & 7)) << 2];
            const uint32_t* bpc = pkb + (size_t)c * BK + k0;
            uint4 w0 = *(const uint4*)(bpc);
            uint4 w1 = *(const uint4*)(bpc + 4);

            // A: sigmoid + exact 3-term split (hi/mid/lo bit-truncation)
            float xs[8] = {a0.x, a0.y, a0.z, a0.w, a1.x, a1.y, a1.z, a1.w};
            uint32_t hu[8], mu[8], lu[8];
#pragma unroll
            for (int i = 0; i < 8; ++i) {
                float x  = xs[i];
                float sg = __builtin_amdgcn_rcpf(1.0f + __expf(-x));
                ps += sg;
                uint32_t u0 = __float_as_uint(sg);
                float hi = __uint_as_float(u0 & 0xFFFF0000u);
                float r1 = sg - hi;                      // exact
                uint32_t u1 = __float_as_uint(r1);
                float mi = __uint_as_float(u1 & 0xFFFF0000u);
                float r2 = r1 - mi;                      // exact, <=8 sig bits
                hu[i] = u0; mu[i] = u1; lu[i] = __float_as_uint(r2);
            }
            union { uint4 u; bf16x8 v; } ah, am, al;
            ah.u = make_uint4(__builtin_amdgcn_perm(hu[1], hu[0], PERM_HI16),
                              __builtin_amdgcn_perm(hu[3], hu[2], PERM_HI16),
                              __builtin_amdgcn_perm(hu[5], hu[4], PERM_HI16),
                              __builtin_amdgcn_perm(hu[7], hu[6], PERM_HI16));
            am.u = make_uint4(__builtin_amdgcn_perm(mu[1], mu[0], PERM_HI16),
                              __builtin_amdgcn_perm(mu[3], mu[2], PERM_HI16),
                              __builtin_amdgcn_perm(mu[5], mu[4], PERM_HI16),
                              __builtin_amdgcn_perm(mu[7], mu[6], PERM_HI16));
            al.u = make_uint4(__builtin_amdgcn_perm(lu[1], lu[0], PERM_HI16),
                              __builtin_amdgcn_perm(lu[3], lu[2], PERM_HI16),
                              __builtin_amdgcn_perm(lu[5], lu[4], PERM_HI16),
                              __builtin_amdgcn_perm(lu[7], lu[6], PERM_HI16));

            // B: word j -> bf16(bit m) in lo16, bf16(bit 16+m) in hi16 (3 ops)
            uint32_t wj[8] = {w0.x, w0.y, w0.z, w0.w, w1.x, w1.y, w1.z, w1.w};
            uint32_t ob[8];
#pragma unroll
            for (int j = 0; j < 8; ++j) {
                uint32_t t = wj[j] >> m;
                ob[j] = (t & 0x10001u) * 0x3F80u;
            }
            union { uint4 u; bf16x8 v; } b0, b1;
            b0.u = make_uint4(__builtin_amdgcn_perm(ob[1], ob[0], PERM_LO16),
                              __builtin_amdgcn_perm(ob[3], ob[2], PERM_LO16),
                              __builtin_amdgcn_perm(ob[5], ob[4], PERM_LO16),
                              __builtin_amdgcn_perm(ob[7], ob[6], PERM_LO16));
            b1.u = make_uint4(__builtin_amdgcn_perm(ob[1], ob[0], PERM_HI16),
                              __builtin_amdgcn_perm(ob[3], ob[2], PERM_HI16),
                              __builtin_amdgcn_perm(ob[5], ob[4], PERM_HI16),
                              __builtin_amdgcn_perm(ob[7], ob[6], PERM_HI16));

            cH0 = __builtin_amdgcn_mfma_f32_16x16x32_bf16(ah.v, b0.v, cH0, 0, 0, 0);
            cL0 = __builtin_amdgcn_mfma_f32_16x16x32_bf16(am.v, b0.v, cL0, 0, 0, 0);
            cL0 = __builtin_amdgcn_mfma_f32_16x16x32_bf16(al.v, b0.v, cL0, 0, 0, 0);
            cH1 = __builtin_amdgcn_mfma_f32_16x16x32_bf16(ah.v, b1.v, cH1, 0, 0, 0);
            cL1 = __builtin_amdgcn_mfma_f32_16x16x32_bf16(am.v, b1.v, cL1, 0, 0, 0);
            cL1 = __builtin_amdgcn_mfma_f32_16x16x32_bf16(al.v, b1.v, cL1, 0, 0, 0);
        }

        // drain own DMA (next buf complete), then wg-wide sync:
        // - all waves done READING buf  -> safe to overwrite next iteration
        // - all waves' DMA into buf^1 landed -> safe to read next iteration
        if (c + 1 < NCH) VM_DRAIN();
        RAW_BARRIER();
    }

    // psum: lanes m, m+16, m+32, m+48 share q-row m (disjoint k)
    ps += __shfl_xor(ps, 16);
    ps += __shfl_xor(ps, 32);
    if (lane < 16) {
        int qg = qt * 16 + m;
        if (qg < QQ) atomicAdd(&psum[b * QP + qg], ps);
    }

    // cross-wave C reduce in LDS (stride 9: gcd(9,32)=1), one atomic set/wg.
    float c8[8];
#pragma unroll
    for (int r = 0; r < 4; ++r) {
        c8[r]     = cH0[r] + cL0[r];
        c8[4 + r] = cH1[r] + cL1[r];
    }
    __syncthreads();                   // full drain OK here (once per kernel)
    float* cred = (float*)sA;
    if (wave > 0) {
        float* dst = cred + ((wave - 1) * 64 + lane) * 9;
#pragma unroll
        for (int r = 0; r < 8; ++r) dst[r] = c8[r];
    }
    __syncthreads();
    if (wave == 0) {
#pragma unroll
        for (int wv = 0; wv < 3; ++wv) {
            const float* sp = cred + (wv * 64 + lane) * 9;
#pragma unroll
            for (int r = 0; r < 8; ++r) c8[r] += sp[r];
        }
        // C layout (16x16, m89): col(n) = lane&15, row(q) = quad*4 + r
#pragma unroll
        for (int r = 0; r < 4; ++r) {
            int qg = qt * 16 + quad * 4 + r;
            if (qg < QQ) {
                atomicAdd(&inter[(b * NGT + m) * QP + qg],      c8[r]);
                atomicAdd(&inter[(b * NGT + 16 + m) * QP + qg], c8[4 + r]);
            }
        }
    }
}

// ---------------------------------------------------------------------------
// K4: fused top-4 + greedy dedup, one block per b (4 waves).
__global__ __launch_bounds__(256) void k_match(const float* __restrict__ inter,
                                               const float* __restrict__ psum,
                                               const float* __restrict__ tsum,
                                               const float* __restrict__ logits,
                                               int* __restrict__ out) {
    int b = blockIdx.x;
    int tid = threadIdx.x, lane = tid & 63, wave = tid >> 6;
    __shared__ int sidx[NGT][TOPK];

    for (int nn = 0; nn < 8; ++nn) {
        int n  = wave * 8 + nn;
        int bn = b * NGT + n;
        float tsn = tsum[bn];
        float v[4];
#pragma unroll
        for (int s = 0; s < 4; ++s) {
            int q = lane + 64 * s;
            if (q < QQ) {
                float iv = inter[(size_t)bn * QP + q];
                float un = psum[b * QP + q] + tsn - iv;
                float l0 = logits[(b * QQ + q) * 2];
                float l1 = logits[(b * QQ + q) * 2 + 1];
                float cl = 1.0f / (1.0f + expf(l0 - l1));
                v[s] = iv / (un + EPSF) * cl;
            } else {
                v[s] = -INFINITY;
            }
        }
        for (int k = 0; k < TOPK; ++k) {
            float bv = -INFINITY;
            int   bi = 0x7fffffff;
#pragma unroll
            for (int s = 0; s < 4; ++s)
                if (v[s] > bv) { bv = v[s]; bi = lane + 64 * s; }
#pragma unroll
            for (int off = 32; off; off >>= 1) {
                float ov = __shfl_xor(bv, off);
                int   oi = __shfl_xor(bi, off);
                if (ov > bv || (ov == bv && oi < bi)) { bv = ov; bi = oi; }
            }
            if (lane == (bi & 63)) v[bi >> 6] = -INFINITY;
            if (lane == 0) sidx[n][k] = bi;
        }
    }
    __syncthreads();

    if (wave == 0) {
        int* src = out;
        int* tgt = out + BB * NGT * TOPK;
        int* val = out + 2 * BB * NGT * TOPK;
        int asg = 0;   // 4 assigned bits: q = lane + 64*slot
        for (int n = 0; n < NGT; ++n) {
            int ids[4] = {sidx[n][0], sidx[n][1], sidx[n][2], sidx[n][3]};
            int newasg = asg;
#pragma unroll
            for (int k = 0; k < TOPK; ++k) {
                int idx = ids[k];                      // uniform across lanes
                int owner = idx & 63, slot = idx >> 6;
                int oasg = __shfl(asg, owner);         // pre-n state
                int taken = (oasg >> slot) & 1;
                if (lane == owner) newasg |= (1 << slot);
                if (lane == 0) {
                    int o = (b * NGT + n) * TOPK + k;
                    src[o] = taken ? -1 : idx;
                    tgt[o] = taken ? -1 : n;
                    val[o] = taken ? 0 : 1;
                }
            }
            asg = newasg;
        }
    }
}

// ---------------------------------------------------------------------------
extern "C" void kernel_launch(void* const* d_in, const int* in_sizes, int n_in,
                              void* d_out, int out_size, void* d_ws, size_t ws_size,
                              hipStream_t stream) {
    const float* pred_masks  = (const float*)d_in[0];  // [4,200,256,256]
    const float* pred_logits = (const float*)d_in[1];  // [4,200,2]
    const float* gt_masks    = (const float*)d_in[2];  // [4,32,256,256]

    uint8_t* ws = (uint8_t*)d_ws;
    uint32_t* packed = (uint32_t*)ws;                   // 1 MB
    float* tsum  = (float*)(ws + (size_t)BB * DD * 4);  // 128
    float* inter = tsum + BB * NGT;                     // 26624 (zeroed by k_pack)
    float* psum  = inter + BB * NGT * QP;               // 832   (zeroed, contiguous)

    k_pack <<<BB * (DD / 1024), 256, 0, stream>>>(gt_masks, packed, inter);
    k_tsum <<<BB * NGT,         256, 0, stream>>>(packed, tsum);
    k_mfma <<<NWG,              256, 0, stream>>>(pred_masks, packed, inter, psum);
    k_match<<<BB,               256, 0, stream>>>(inter, psum, tsum, pred_logits, (int*)d_out);
}